// Round 5
// baseline (327.618 us; speedup 1.0000x reference)
//
#include <hip/hip_runtime.h>
#include <hip/hip_cooperative_groups.h>

namespace cg = cooperative_groups;

// N=100000, E=3200000, H=256, G=128.
// R11: single cooperative kernel. Evidence so far:
//  - R9/R10: global f32 atomics execute memory-side (~20G/s, 32B write/atomic,
//    WRITE_SIZE 99.8MB for 400KB dst) at ANY scope -> scatter must stay LDS.
//  - R7: atomic slot reservation (200K global atomics) was SLOWER than the
//    deterministic scan kernel it replaced -> keep deterministic offsets.
//  - R6 131.9us total = ~44us harness ws-fill (fixed tax) + kernels + ~5us
//    per dispatch boundary. So: fuse count/scan/scatter/reduce into ONE
//    dispatch with grid.sync() phases; zero flags in-kernel (no memset).
// Phases (512 blocks x 512 thr, 2/CU):
//  P0 histogram dst chunk -> cnt[blk][b]; local excl scan -> lbase (persists).
//  P1 block b<NB scans cnt[*][b] across blocks -> off[blk][b], tot[b].
//  P2 re-read edges (dst L2-hot), LDS counting-sort, coalesced run writeout
//     into pairs[b*CAP + off + i] ((src<<8)|dst&255).
//  P3 block b<NB: stream bucket pairs, LDS acc via ds atomics, collapsed MLP
//     f(a)=sum_k relu(a*Wl[k]+bl[k])*Wo[k] split-k over 2x256 threads,
//     per-graph LDS pool, sparse global adds, ticket epilogue -> out[G].

#define GMAX  128      // max graphs
#define HMAX  256      // max hidden dim
#define BS    256      // nodes per bucket (dst >> 8)
#define NBMAX 512      // max buckets (N <= 131072)
#define NG    512      // cooperative grid (2 blocks/CU x 256 CUs)
#define BLKT  512      // threads per block
#define CEDGE 6400     // LDS sort capacity (>= QpB*4 + 4)

__global__ __launch_bounds__(BLKT, 4) void fused(
    const int* __restrict__ ei, const float* __restrict__ x,
    const int* __restrict__ batch, const float* __restrict__ Wl,
    const float* __restrict__ bl, const float* __restrict__ Wo,
    const float* __restrict__ bo,
    unsigned* __restrict__ cnt, unsigned* __restrict__ off,
    unsigned* __restrict__ tot, float* __restrict__ gsum,
    float* __restrict__ gcnt, unsigned* __restrict__ done,
    unsigned* __restrict__ pairs, float* __restrict__ out,
    int N, int E, int H, int G, int NB, int QpB, int CAP) {
  __shared__ unsigned lp[CEDGE];        // sorted pairs
  __shared__ unsigned short lb[CEDGE];  // bucket id per sorted slot
  __shared__ unsigned hist[NBMAX];      // block-local counts   (persists P0->P2)
  __shared__ unsigned sc[NBMAX];        // scan / float scratch
  __shared__ unsigned lbase[NBMAX];     // local excl scan      (persists P0->P3)
  __shared__ unsigned lrank[NBMAX];     // running rank
  __shared__ unsigned hb[NBMAX];        // global write base per bucket
  __shared__ float sWl[HMAX], sbl[HMAX], sWo[HMAX];
  __shared__ float ls[GMAX], lc[GMAX], acc[BS];
  __shared__ unsigned ticket;

  cg::grid_group grid = cg::this_grid();
  int tid = threadIdx.x, blk = blockIdx.x;
  int ngrid = (int)gridDim.x;

  // ---- P0: per-block histogram of dst buckets + local exclusive scan ----
  for (int b = tid; b < NBMAX; b += BLKT) { hist[b] = 0u; lrank[b] = 0u; }
  __syncthreads();

  int Q = E >> 2;
  int q0 = blk * QpB;
  int q1 = min(q0 + QpB, Q);
  const int4* s4 = (const int4*)ei;
  const int4* d4 = (const int4*)(ei + E);

  for (int q = q0 + tid; q < q1; q += BLKT) {
    int4 d = d4[q];
    atomicAdd(&hist[d.x >> 8], 1u);
    atomicAdd(&hist[d.y >> 8], 1u);
    atomicAdd(&hist[d.z >> 8], 1u);
    atomicAdd(&hist[d.w >> 8], 1u);
  }
  if (blk == 0)   // tail edges (E % 4)
    for (int e = (Q << 2) + tid; e < E; e += BLKT)
      atomicAdd(&hist[ei[E + e] >> 8], 1u);
  __syncthreads();

  for (int b = tid; b < NBMAX; b += BLKT) sc[b] = hist[b];
  __syncthreads();
  for (int o = 1; o < NBMAX; o <<= 1) {
    unsigned v = 0u;
    if (tid < NBMAX && tid >= o) v = sc[tid - o];
    __syncthreads();
    if (tid < NBMAX) sc[tid] += v;
    __syncthreads();
  }
  for (int b = tid; b < NBMAX; b += BLKT) lbase[b] = sc[b] - hist[b];
  for (int b = tid; b < NB; b += BLKT)
    cnt[(size_t)blk * NBMAX + b] = hist[b];   // coalesced row write
  // last block zeros flags via agent-scope stores (visible to memory-side RMW)
  if (blk == ngrid - 1) {
    if (tid < GMAX) {
      __hip_atomic_store(&gsum[tid], 0.f, __ATOMIC_RELAXED, __HIP_MEMORY_SCOPE_AGENT);
      __hip_atomic_store(&gcnt[tid], 0.f, __ATOMIC_RELAXED, __HIP_MEMORY_SCOPE_AGENT);
    }
    if (tid == 0)
      __hip_atomic_store(done, 0u, __ATOMIC_RELAXED, __HIP_MEMORY_SCOPE_AGENT);
  }
  grid.sync();

  // ---- P1: cross-block exclusive scan per bucket (block b handles bucket b) ----
  if (blk < NB) {
    unsigned c = (tid < ngrid) ? cnt[(size_t)tid * NBMAX + blk] : 0u;
    sc[tid] = c;
    __syncthreads();
    for (int o = 1; o < BLKT; o <<= 1) {
      unsigned v = (tid >= o) ? sc[tid - o] : 0u;
      __syncthreads();
      sc[tid] += v;
      __syncthreads();
    }
    if (tid < ngrid) off[(size_t)tid * NBMAX + blk] = sc[tid] - c;
    if (tid == BLKT - 1) tot[blk] = sc[tid];
  }
  grid.sync();

  // ---- P2: LDS counting-sort + coalesced run writeout ----
  for (int b = tid; b < NB; b += BLKT)
    hb[b] = (unsigned)b * (unsigned)CAP + off[(size_t)blk * NBMAX + b];
  __syncthreads();

  for (int q = q0 + tid; q < q1; q += BLKT) {
    int4 s = s4[q];
    int4 d = d4[q];   // L2-hot re-read (chunk read in P0)
    { int b = d.x >> 8; unsigned r = atomicAdd(&lrank[b], 1u);
      unsigned p = lbase[b] + r;
      lp[p] = ((unsigned)s.x << 8) | (unsigned)(d.x & 255); lb[p] = (unsigned short)b; }
    { int b = d.y >> 8; unsigned r = atomicAdd(&lrank[b], 1u);
      unsigned p = lbase[b] + r;
      lp[p] = ((unsigned)s.y << 8) | (unsigned)(d.y & 255); lb[p] = (unsigned short)b; }
    { int b = d.z >> 8; unsigned r = atomicAdd(&lrank[b], 1u);
      unsigned p = lbase[b] + r;
      lp[p] = ((unsigned)s.z << 8) | (unsigned)(d.z & 255); lb[p] = (unsigned short)b; }
    { int b = d.w >> 8; unsigned r = atomicAdd(&lrank[b], 1u);
      unsigned p = lbase[b] + r;
      lp[p] = ((unsigned)s.w << 8) | (unsigned)(d.w & 255); lb[p] = (unsigned short)b; }
  }
  int total = (q1 - q0) * 4;
  if (blk == 0) {            // tail edges (E % 4)
    for (int e = (Q << 2) + tid; e < E; e += BLKT) {
      int d = ei[E + e], s = ei[e];
      int b = d >> 8; unsigned r = atomicAdd(&lrank[b], 1u);
      unsigned p = lbase[b] + r;
      lp[p] = ((unsigned)s << 8) | (unsigned)(d & 255); lb[p] = (unsigned short)b;
    }
    total += (E & 3);
  }
  if (total > CEDGE) total = CEDGE;   // safety (host gates this)
  __syncthreads();

  unsigned capu = (unsigned)CAP;
  for (int i = tid; i < total; i += BLKT) {
    unsigned b = lb[i];
    unsigned slot = hb[b] + ((unsigned)i - lbase[b]);
    if (slot < (b + 1u) * capu)       // clamp: never corrupt neighbors
      pairs[slot] = lp[i];
  }
  // preload P3 state while we're here
  if (tid < H) { sWl[tid] = Wl[tid]; sbl[tid] = bl[tid]; sWo[tid] = Wo[tid]; }
  if (tid < GMAX) { ls[tid] = 0.f; lc[tid] = 0.f; }
  if (tid < BS) acc[tid] = 0.f;
  grid.sync();

  // ---- P3: bucket reduce + collapsed MLP + per-graph pooling ----
  if (blk < NB) {
    unsigned lo = (unsigned)blk * (unsigned)CAP;
    unsigned c = min(tot[blk], (unsigned)CAP);
    unsigned q4 = c >> 2;
    const uint4* p4 = (const uint4*)(pairs + lo);   // CAP%4==0 -> aligned
    for (unsigned i = tid; i < q4; i += BLKT) {
      uint4 p = p4[i];
      atomicAdd(&acc[p.x & 255u], x[p.x >> 8]);
      atomicAdd(&acc[p.y & 255u], x[p.y >> 8]);
      atomicAdd(&acc[p.z & 255u], x[p.z >> 8]);
      atomicAdd(&acc[p.w & 255u], x[p.w >> 8]);
    }
    if (tid < (int)(c & 3u)) {
      unsigned p = pairs[lo + (q4 << 2) + tid];
      atomicAdd(&acc[p & 255u], x[p >> 8]);
    }
    __syncthreads();

    // split-k MLP: threads (ln, ln+256) each do half the k-range of node ln
    int half = tid >> 8;          // 0 or 1
    int ln = tid & 255;
    int node = blk * BS + ln;
    float f = 0.f;
    if (node < N) {
      float a = acc[ln];
#pragma unroll 8
      for (int k = half; k < H; k += 2) {
        float hh = fmaf(a, sWl[k], sbl[k]);
        f = fmaf(fmaxf(hh, 0.f), sWo[k], f);
      }
    }
    ((float*)sc)[tid] = f;        // sc free since P1
    __syncthreads();
    if (tid < BS) {
      int nd = blk * BS + tid;
      if (nd < N) {
        float ff = ((float*)sc)[tid] + ((float*)sc)[tid + BS];
        int g = batch[nd];
        atomicAdd(&ls[g], ff);
        atomicAdd(&lc[g], 1.f);
      }
    }
  }
  __syncthreads();
  if (tid < GMAX && lc[tid] != 0.f) {
    atomicAdd(&gsum[tid], ls[tid]);   // sparse: ~1-2 graphs per bucket
    atomicAdd(&gcnt[tid], lc[tid]);
  }
  __syncthreads();
  if (tid == 0)
    ticket = __hip_atomic_fetch_add(done, 1u, __ATOMIC_ACQ_REL,
                                    __HIP_MEMORY_SCOPE_AGENT);
  __syncthreads();
  if (ticket == (unsigned)ngrid - 1u && tid < G) {
    float s = __hip_atomic_load(&gsum[tid], __ATOMIC_RELAXED, __HIP_MEMORY_SCOPE_AGENT);
    float c = __hip_atomic_load(&gcnt[tid], __ATOMIC_RELAXED, __HIP_MEMORY_SCOPE_AGENT);
    out[tid] = fmaxf(s / fmaxf(c, 1.f) + bo[0], 0.f);
  }
}

// ---------------- fallback path (guards fail / no cooperative capacity) ----------------

__global__ __launch_bounds__(256) void fb_scatter(const int* __restrict__ ei,
                                                  const float* __restrict__ x,
                                                  float* __restrict__ agg, int E) {
  int t = blockIdx.x * blockDim.x + threadIdx.x;
  if (t < E) atomicAdd(&agg[ei[E + t]], x[ei[t]]);
}

__global__ __launch_bounds__(256) void fb_node(const float* __restrict__ agg,
                                               const int* __restrict__ batch,
                                               const float* __restrict__ Wl,
                                               const float* __restrict__ bl,
                                               const float* __restrict__ Wo,
                                               float* __restrict__ gsum,
                                               float* __restrict__ gcnt, int N, int H) {
  __shared__ float sWl[HMAX], sbl[HMAX], sWo[HMAX];
  __shared__ float ls[GMAX], lc[GMAX];
  int tid = threadIdx.x;
  if (tid < H) { sWl[tid] = Wl[tid]; sbl[tid] = bl[tid]; sWo[tid] = Wo[tid]; }
  if (tid < GMAX) { ls[tid] = 0.f; lc[tid] = 0.f; }
  __syncthreads();
  int i = blockIdx.x * blockDim.x + tid;
  if (i < N) {
    float a = agg[i], f = 0.f;
    for (int k = 0; k < H; ++k) {
      float hh = fmaf(a, sWl[k], sbl[k]);
      f = fmaf(fmaxf(hh, 0.f), sWo[k], f);
    }
    int g = batch[i];
    atomicAdd(&ls[g], f);
    atomicAdd(&lc[g], 1.f);
  }
  __syncthreads();
  if (tid < GMAX && lc[tid] != 0.f) {
    atomicAdd(&gsum[tid], ls[tid]);
    atomicAdd(&gcnt[tid], lc[tid]);
  }
}

__global__ void fb_final(const float* __restrict__ gsum,
                         const float* __restrict__ gcnt,
                         const float* __restrict__ b_out,
                         float* __restrict__ out, int G) {
  int g = blockIdx.x * blockDim.x + threadIdx.x;
  if (g < G) out[g] = fmaxf(gsum[g] / fmaxf(gcnt[g], 1.f) + b_out[0], 0.f);
}

// ---------------- launch ----------------

extern "C" void kernel_launch(void* const* d_in, const int* in_sizes, int n_in,
                              void* d_out, int out_size, void* d_ws, size_t ws_size,
                              hipStream_t stream) {
  const float* x     = (const float*)d_in[0];
  const int*   ei    = (const int*)d_in[1];
  const int*   batch = (const int*)d_in[2];
  const float* Wl    = (const float*)d_in[3];
  const float* bl    = (const float*)d_in[4];
  const float* Wo    = (const float*)d_in[5];
  const float* bo    = (const float*)d_in[6];
  float* out = (float*)d_out;

  int N = in_sizes[0];        // 100000
  int E = in_sizes[1] / 2;    // 3200000
  int H = in_sizes[3];        // 256
  int G = out_size;           // 128

  int NB = (N + BS - 1) / BS; // 391
  int Q   = E >> 2;
  int QpB = (Q + NG - 1) / NG;

  int avg = (NB > 0) ? E / NB : 0;
  int CAP = (2 * avg + 4095) & ~4095;
  if (CAP < 4096) CAP = 4096;

  // ws word layout:
  //   cnt[NG*NBMAX] | off[NG*NBMAX] | tot[NBMAX]
  //   gsum[GMAX] | gcnt[GMAX] | done[4] | pairs[NB*CAP]
  const size_t W_MAT = (size_t)NG * NBMAX;
  const size_t HDRW  = 2 * W_MAT + NBMAX + 2 * GMAX + 4;
  size_t need = (HDRW + (size_t)NB * (size_t)CAP) * 4u;

  int occ = 0;
  hipError_t oe = hipOccupancyMaxActiveBlocksPerMultiprocessor(&occ, fused, BLKT, 0);
  bool ok = (oe == hipSuccess) && (occ >= 2) &&
            NB <= NBMAX && ws_size >= need && H <= HMAX && G <= GMAX &&
            QpB * 4 + 4 <= CEDGE;

  if (ok) {
    unsigned* cnt   = (unsigned*)d_ws;
    unsigned* off   = cnt + W_MAT;
    unsigned* tot   = off + W_MAT;
    float*    gsum  = (float*)(tot + NBMAX);
    float*    gcnt  = gsum + GMAX;
    unsigned* done  = (unsigned*)(gcnt + GMAX);
    unsigned* pairs = done + 4;

    void* args[] = {(void*)&ei, (void*)&x, (void*)&batch, (void*)&Wl,
                    (void*)&bl, (void*)&Wo, (void*)&bo,
                    (void*)&cnt, (void*)&off, (void*)&tot,
                    (void*)&gsum, (void*)&gcnt, (void*)&done,
                    (void*)&pairs, (void*)&out,
                    (void*)&N, (void*)&E, (void*)&H, (void*)&G,
                    (void*)&NB, (void*)&QpB, (void*)&CAP};
    hipError_t le = hipLaunchCooperativeKernel((const void*)fused,
                                               dim3(NG), dim3(BLKT),
                                               args, 0, stream);
    if (le == hipSuccess) return;
    // fall through to fallback on launch failure
  }

  float* agg  = (float*)d_ws;
  float* gsum = agg + N;
  float* gcnt = gsum + GMAX;
  hipMemsetAsync(d_ws, 0, ((size_t)N + 2 * GMAX) * 4u, stream);
  fb_scatter<<<(E + 255) / 256, 256, 0, stream>>>(ei, x, agg, E);
  fb_node<<<(N + 255) / 256, 256, 0, stream>>>(agg, batch, Wl, bl, Wo,
                                               gsum, gcnt, N, H);
  fb_final<<<1, 256, 0, stream>>>(gsum, gcnt, bo, out, G);
}

// Round 6
// 126.206 us; speedup vs baseline: 2.5959x; 2.5959x over previous
//
#include <hip/hip_runtime.h>

// N=100000, E=3200000, H=256, G=128.
// R12: sort-free chunk x range partials. Evidence chain:
//  - R9/R10: global f32 atomics are memory-side at ANY scope (~20G/s, 32B
//    write-through each) -> scatter must aggregate in LDS.
//  - R11: cooperative grid.sync ~50us each -> no single-kernel fusion.
//  - R11 counters: pipeline traffic ~52MB (~8us) but time is latency/barrier
//    stall; harness re-poison fills (~88us, 2x 256MiB) are INSIDE dur_us.
//    So kernels are ~44us of the 131.9 best; target the sort machinery.
// Structure (2 dispatches, no memset):
//  P1: grid (8 ranges x 64 chunks). Block (r,j) streams edge chunk j
//      (coalesced int4), filters dst in range r (range test only),
//      acc[dst-lo] += x[src] via LDS f32 atomics (52KB slab), then dumps the
//      slab coalesced to partial[(r*64+j)]. Same-chunk blocks are id=j mod 64
//      -> same XCD under round-robin -> chunk re-reads are L2-hits
//      (8 chunks x 400KB = 3.2MB < 4MB L2/XCD); L3 backstops otherwise.
//      Block 0 zeroes gsum/gcnt/done (visible to P2 at dispatch boundary).
//  P2: per node: a = sum_j partial[r][j][li] (64 coalesced reads), collapsed
//      MLP f(a)=sum_k relu(a*Wl[k]+bl[k])*Wo[k], per-graph LDS pooling,
//      sparse device atomics, ticket epilogue -> out = relu(mean + b_out).

#define GMAX 128       // max graphs
#define HMAX 256       // max hidden dim
#define RNG  8         // node ranges (LDS-sized)
#define CHK  64        // edge chunks
#define RLDS 13056     // LDS accumulator words per range (>= ceil(N/RNG)), %64==0
#define HDRW 272       // header words (gsum,gcnt,done + pad to 16B)

// ---------------- main path ----------------

__global__ __launch_bounds__(512, 6) void p1_scatter(
    const int* __restrict__ ei, const float* __restrict__ x,
    float* __restrict__ partial, float* __restrict__ gsum,
    float* __restrict__ gcnt, unsigned* __restrict__ done,
    int E, int N, int RANGE, int QpC) {
  __shared__ __align__(16) float acc[RLDS];
  int tid = threadIdx.x, blk = blockIdx.x;
  int r = blk >> 6;          // node range id   [0,8)
  int j = blk & 63;          // edge chunk id   [0,64)  -> XCD = j%8 (round-robin)
  for (int i = tid; i < RLDS; i += 512) acc[i] = 0.f;
  if (blk == 0) {            // zero epilogue state for P2 (ws is poisoned)
    if (tid < GMAX) { gsum[tid] = 0.f; gcnt[tid] = 0.f; }
    if (tid == 0) done[0] = 0u;
  }
  __syncthreads();

  int lo = r * RANGE;
  int hi = min(lo + RANGE, N);
  int Q = E >> 2;
  int q0 = j * QpC, q1 = min(q0 + QpC, Q);
  const int4* s4 = (const int4*)ei;
  const int4* d4 = (const int4*)(ei + E);
  for (int q = q0 + tid; q < q1; q += 512) {
    int4 s = s4[q];
    int4 d = d4[q];
    if (d.x >= lo && d.x < hi) atomicAdd(&acc[d.x - lo], x[s.x]);
    if (d.y >= lo && d.y < hi) atomicAdd(&acc[d.y - lo], x[s.y]);
    if (d.z >= lo && d.z < hi) atomicAdd(&acc[d.z - lo], x[s.z]);
    if (d.w >= lo && d.w < hi) atomicAdd(&acc[d.w - lo], x[s.w]);
  }
  if (j == 0) {              // tail edges (E % 4): the 8 j==0 blocks filter
    for (int e = (Q << 2) + tid; e < E; e += 512) {
      int d = ei[E + e];
      if (d >= lo && d < hi) atomicAdd(&acc[d - lo], x[ei[e]]);
    }
  }
  __syncthreads();

  // coalesced slab dump (full RLDS incl zero pad; P2 reads only li < RANGE)
  float4* dst = (float4*)(partial + (size_t)blk * RLDS);
  const float4* a4 = (const float4*)acc;
  for (int i = tid; i < RLDS / 4; i += 512) dst[i] = a4[i];
}

__global__ __launch_bounds__(256, 4) void p2_node(
    const float* __restrict__ partial, const int* __restrict__ batch,
    const float* __restrict__ Wl, const float* __restrict__ bl,
    const float* __restrict__ Wo, const float* __restrict__ bo,
    float* __restrict__ gsum, float* __restrict__ gcnt,
    unsigned* __restrict__ done, float* __restrict__ out,
    int N, int H, int G, int RANGE, int BPR) {
  __shared__ float sWl[HMAX], sbl[HMAX], sWo[HMAX];
  __shared__ float ls[GMAX], lc[GMAX];
  __shared__ unsigned ticket;
  int tid = threadIdx.x, blk = blockIdx.x;
  if (tid < H) { sWl[tid] = Wl[tid]; sbl[tid] = bl[tid]; sWo[tid] = Wo[tid]; }
  if (tid < GMAX) { ls[tid] = 0.f; lc[tid] = 0.f; }
  __syncthreads();

  int r = blk / BPR;
  int li = (blk % BPR) * 256 + tid;
  int node = r * RANGE + li;
  if (li < RANGE && node < N) {
    // 64-way partial sum: coalesced across lanes, 8-deep ILP across slabs
    const float* p = partial + (size_t)(r * CHK) * RLDS + li;
    float a = 0.f;
#pragma unroll 8
    for (int c = 0; c < CHK; ++c) a += p[(size_t)c * RLDS];
    float f = 0.f;
#pragma unroll 8
    for (int k = 0; k < H; ++k) {
      float hh = fmaf(a, sWl[k], sbl[k]);
      f = fmaf(fmaxf(hh, 0.f), sWo[k], f);
    }
    int g = batch[node];
    atomicAdd(&ls[g], f);
    atomicAdd(&lc[g], 1.f);
  }
  __syncthreads();
  if (tid < GMAX && lc[tid] != 0.f) {
    atomicAdd(&gsum[tid], ls[tid]);   // sparse: batch sorted -> ~1-2 graphs/blk
    atomicAdd(&gcnt[tid], lc[tid]);
  }
  __syncthreads();
  if (tid == 0)
    ticket = __hip_atomic_fetch_add(done, 1u, __ATOMIC_ACQ_REL,
                                    __HIP_MEMORY_SCOPE_AGENT);
  __syncthreads();
  if (ticket == gridDim.x - 1 && tid < G) {
    float s = __hip_atomic_load(&gsum[tid], __ATOMIC_RELAXED, __HIP_MEMORY_SCOPE_AGENT);
    float c = __hip_atomic_load(&gcnt[tid], __ATOMIC_RELAXED, __HIP_MEMORY_SCOPE_AGENT);
    out[tid] = fmaxf(s / fmaxf(c, 1.f) + bo[0], 0.f);
  }
}

// ---------------- fallback path (guards fail) ----------------

__global__ __launch_bounds__(256) void fb_scatter(const int* __restrict__ ei,
                                                  const float* __restrict__ x,
                                                  float* __restrict__ agg, int E) {
  int t = blockIdx.x * blockDim.x + threadIdx.x;
  if (t < E) atomicAdd(&agg[ei[E + t]], x[ei[t]]);
}

__global__ __launch_bounds__(256) void fb_node(const float* __restrict__ agg,
                                               const int* __restrict__ batch,
                                               const float* __restrict__ Wl,
                                               const float* __restrict__ bl,
                                               const float* __restrict__ Wo,
                                               float* __restrict__ gsum,
                                               float* __restrict__ gcnt, int N, int H) {
  __shared__ float sWl[HMAX], sbl[HMAX], sWo[HMAX];
  __shared__ float ls[GMAX], lc[GMAX];
  int tid = threadIdx.x;
  if (tid < H) { sWl[tid] = Wl[tid]; sbl[tid] = bl[tid]; sWo[tid] = Wo[tid]; }
  if (tid < GMAX) { ls[tid] = 0.f; lc[tid] = 0.f; }
  __syncthreads();
  int i = blockIdx.x * blockDim.x + tid;
  if (i < N) {
    float a = agg[i], f = 0.f;
    for (int k = 0; k < H; ++k) {
      float hh = fmaf(a, sWl[k], sbl[k]);
      f = fmaf(fmaxf(hh, 0.f), sWo[k], f);
    }
    int g = batch[i];
    atomicAdd(&ls[g], f);
    atomicAdd(&lc[g], 1.f);
  }
  __syncthreads();
  if (tid < GMAX && lc[tid] != 0.f) {
    atomicAdd(&gsum[tid], ls[tid]);
    atomicAdd(&gcnt[tid], lc[tid]);
  }
}

__global__ void fb_final(const float* __restrict__ gsum,
                         const float* __restrict__ gcnt,
                         const float* __restrict__ b_out,
                         float* __restrict__ out, int G) {
  int g = blockIdx.x * blockDim.x + threadIdx.x;
  if (g < G) out[g] = fmaxf(gsum[g] / fmaxf(gcnt[g], 1.f) + b_out[0], 0.f);
}

// ---------------- launch ----------------

extern "C" void kernel_launch(void* const* d_in, const int* in_sizes, int n_in,
                              void* d_out, int out_size, void* d_ws, size_t ws_size,
                              hipStream_t stream) {
  const float* x     = (const float*)d_in[0];
  const int*   ei    = (const int*)d_in[1];
  const int*   batch = (const int*)d_in[2];
  const float* Wl    = (const float*)d_in[3];
  const float* bl    = (const float*)d_in[4];
  const float* Wo    = (const float*)d_in[5];
  const float* bo    = (const float*)d_in[6];
  float* out = (float*)d_out;

  int N = in_sizes[0];        // 100000
  int E = in_sizes[1] / 2;    // 3200000
  int H = in_sizes[3];        // 256
  int G = out_size;           // 128

  int RANGE = (N + RNG - 1) / RNG;           // 12500
  int Q     = E >> 2;
  int QpC   = (Q + CHK - 1) / CHK;           // 12500 quads/chunk

  // ws layout (words): gsum[GMAX] | gcnt[GMAX] | done[..] | pad -> HDRW |
  //                    partial[RNG*CHK][RLDS]
  size_t need = ((size_t)HDRW + (size_t)RNG * CHK * RLDS) * 4u;

  if (RANGE <= RLDS && H <= HMAX && G <= GMAX && ws_size >= need && N > 0) {
    float*    w     = (float*)d_ws;
    float*    gsum  = w;
    float*    gcnt  = w + GMAX;
    unsigned* done  = (unsigned*)(w + 2 * GMAX);
    float*    partial = w + HDRW;

    p1_scatter<<<RNG * CHK, 512, 0, stream>>>(ei, x, partial, gsum, gcnt,
                                              done, E, N, RANGE, QpC);
    int BPR = (RANGE + 255) / 256;           // blocks per range (49)
    p2_node<<<RNG * BPR, 256, 0, stream>>>(partial, batch, Wl, bl, Wo, bo,
                                           gsum, gcnt, done, out,
                                           N, H, G, RANGE, BPR);
  } else {
    float* agg  = (float*)d_ws;
    float* gsum = agg + N;
    float* gcnt = gsum + GMAX;
    hipMemsetAsync(d_ws, 0, ((size_t)N + 2 * GMAX) * 4u, stream);
    fb_scatter<<<(E + 255) / 256, 256, 0, stream>>>(ei, x, agg, E);
    fb_node<<<(N + 255) / 256, 256, 0, stream>>>(agg, batch, Wl, bl, Wo,
                                                 gsum, gcnt, N, H);
    fb_final<<<1, 256, 0, stream>>>(gsum, gcnt, bo, out, G);
  }
}

// Round 7
// 125.245 us; speedup vs baseline: 2.6158x; 1.0077x over previous
//
#include <hip/hip_runtime.h>

// N=100000, E=3200000, H=256, G=128.
// R13: R12 structure + occupancy fix. Evidence chain:
//  - R9/R10: global f32 atomics are memory-side at ANY scope -> LDS agg only.
//  - R11: grid.sync ~50us each -> no cooperative fusion.
//  - R12: p1_scatter 44.2us, VALUBusy 11.6%, occ 34% (grid 512 = 2 blk/CU),
//    FETCH 14MB (XCD L2 sharing works) -> latency-bound, not BW/VALU-bound.
// Fix: CHK 64->96 => grid 768 = exactly 3 blocks/CU (LDS 52224*3 = 156.7KB
// <= 160KB), 24 waves/CU = 75% occupancy. 96%8==0 keeps same-chunk blocks on
// one XCD (per-XCD footprint 12 chunks x 267KB = 3.2MB < 4MB L2).
// Also: unsigned single-compare range test, unroll-2 for load ILP.
//  P1: block (r,j) streams edge chunk j, filters dst in range r,
//      acc[dst-lo] += x[src] via LDS f32 atomics, slab -> partial[r*96+j].
//      Block 0 zeroes gsum/gcnt/done (visible to P2 at dispatch boundary).
//  P2: a = sum_j partial[r][j][li] (96 coalesced reads), collapsed MLP
//      f(a)=sum_k relu(a*Wl[k]+bl[k])*Wo[k], per-graph LDS pooling, sparse
//      device atomics, ticket epilogue -> out = relu(mean + b_out).

#define GMAX 128       // max graphs
#define HMAX 256       // max hidden dim
#define RNG  8         // node ranges (LDS-sized)
#define CHK  96        // edge chunks (%8==0 for XCD affinity; grid=768=3/CU)
#define RLDS 13056     // LDS accumulator words per range (>= ceil(N/RNG))
#define HDRW 272       // header words (gsum,gcnt,done + pad to 16B)

// ---------------- main path ----------------

__global__ __launch_bounds__(512, 6) void p1_scatter(
    const int* __restrict__ ei, const float* __restrict__ x,
    float* __restrict__ partial, float* __restrict__ gsum,
    float* __restrict__ gcnt, unsigned* __restrict__ done,
    int E, int N, int RANGE, int QpC) {
  __shared__ __align__(16) float acc[RLDS];
  int tid = threadIdx.x, blk = blockIdx.x;
  int r = blk / CHK;         // node range id   [0,RNG)
  int j = blk % CHK;         // edge chunk id   [0,CHK) -> XCD = j%8
  for (int i = tid; i < RLDS; i += 512) acc[i] = 0.f;
  if (blk == 0) {            // zero epilogue state for P2 (ws is poisoned)
    if (tid < GMAX) { gsum[tid] = 0.f; gcnt[tid] = 0.f; }
    if (tid == 0) done[0] = 0u;
  }
  __syncthreads();

  int lo = r * RANGE;
  unsigned span = (unsigned)(min(lo + RANGE, N) - lo);
  int Q = E >> 2;
  int q0 = j * QpC, q1 = min(q0 + QpC, Q);
  const int4* s4 = (const int4*)ei;
  const int4* d4 = (const int4*)(ei + E);
#pragma unroll 2
  for (int q = q0 + tid; q < q1; q += 512) {
    int4 s = s4[q];
    int4 d = d4[q];
    unsigned ux = (unsigned)(d.x - lo), uy = (unsigned)(d.y - lo);
    unsigned uz = (unsigned)(d.z - lo), uw = (unsigned)(d.w - lo);
    if (ux < span) atomicAdd(&acc[ux], x[s.x]);
    if (uy < span) atomicAdd(&acc[uy], x[s.y]);
    if (uz < span) atomicAdd(&acc[uz], x[s.z]);
    if (uw < span) atomicAdd(&acc[uw], x[s.w]);
  }
  if (j == 0) {              // tail edges (E % 4): the RNG j==0 blocks filter
    for (int e = (Q << 2) + tid; e < E; e += 512) {
      unsigned u = (unsigned)(ei[E + e] - lo);
      if (u < span) atomicAdd(&acc[u], x[ei[e]]);
    }
  }
  __syncthreads();

  // coalesced slab dump (full RLDS incl zero pad; P2 reads only li < RANGE)
  float4* dst = (float4*)(partial + (size_t)blk * RLDS);
  const float4* a4 = (const float4*)acc;
  for (int i = tid; i < RLDS / 4; i += 512) dst[i] = a4[i];
}

__global__ __launch_bounds__(256, 4) void p2_node(
    const float* __restrict__ partial, const int* __restrict__ batch,
    const float* __restrict__ Wl, const float* __restrict__ bl,
    const float* __restrict__ Wo, const float* __restrict__ bo,
    float* __restrict__ gsum, float* __restrict__ gcnt,
    unsigned* __restrict__ done, float* __restrict__ out,
    int N, int H, int G, int RANGE, int BPR) {
  __shared__ float sWl[HMAX], sbl[HMAX], sWo[HMAX];
  __shared__ float ls[GMAX], lc[GMAX];
  __shared__ unsigned ticket;
  int tid = threadIdx.x, blk = blockIdx.x;
  if (tid < H) { sWl[tid] = Wl[tid]; sbl[tid] = bl[tid]; sWo[tid] = Wo[tid]; }
  if (tid < GMAX) { ls[tid] = 0.f; lc[tid] = 0.f; }
  __syncthreads();

  int r = blk / BPR;
  int li = (blk % BPR) * 256 + tid;
  int node = r * RANGE + li;
  if (li < RANGE && node < N) {
    // CHK-way partial sum: coalesced across lanes, 8-deep ILP across slabs
    const float* p = partial + (size_t)(r * CHK) * RLDS + li;
    float a = 0.f;
#pragma unroll 8
    for (int c = 0; c < CHK; ++c) a += p[(size_t)c * RLDS];
    float f = 0.f;
#pragma unroll 8
    for (int k = 0; k < H; ++k) {
      float hh = fmaf(a, sWl[k], sbl[k]);
      f = fmaf(fmaxf(hh, 0.f), sWo[k], f);
    }
    int g = batch[node];
    atomicAdd(&ls[g], f);
    atomicAdd(&lc[g], 1.f);
  }
  __syncthreads();
  if (tid < GMAX && lc[tid] != 0.f) {
    atomicAdd(&gsum[tid], ls[tid]);   // sparse: batch sorted -> ~1-2 graphs/blk
    atomicAdd(&gcnt[tid], lc[tid]);
  }
  __syncthreads();
  if (tid == 0)
    ticket = __hip_atomic_fetch_add(done, 1u, __ATOMIC_ACQ_REL,
                                    __HIP_MEMORY_SCOPE_AGENT);
  __syncthreads();
  if (ticket == gridDim.x - 1 && tid < G) {
    float s = __hip_atomic_load(&gsum[tid], __ATOMIC_RELAXED, __HIP_MEMORY_SCOPE_AGENT);
    float c = __hip_atomic_load(&gcnt[tid], __ATOMIC_RELAXED, __HIP_MEMORY_SCOPE_AGENT);
    out[tid] = fmaxf(s / fmaxf(c, 1.f) + bo[0], 0.f);
  }
}

// ---------------- fallback path (guards fail) ----------------

__global__ __launch_bounds__(256) void fb_scatter(const int* __restrict__ ei,
                                                  const float* __restrict__ x,
                                                  float* __restrict__ agg, int E) {
  int t = blockIdx.x * blockDim.x + threadIdx.x;
  if (t < E) atomicAdd(&agg[ei[E + t]], x[ei[t]]);
}

__global__ __launch_bounds__(256) void fb_node(const float* __restrict__ agg,
                                               const int* __restrict__ batch,
                                               const float* __restrict__ Wl,
                                               const float* __restrict__ bl,
                                               const float* __restrict__ Wo,
                                               float* __restrict__ gsum,
                                               float* __restrict__ gcnt, int N, int H) {
  __shared__ float sWl[HMAX], sbl[HMAX], sWo[HMAX];
  __shared__ float ls[GMAX], lc[GMAX];
  int tid = threadIdx.x;
  if (tid < H) { sWl[tid] = Wl[tid]; sbl[tid] = bl[tid]; sWo[tid] = Wo[tid]; }
  if (tid < GMAX) { ls[tid] = 0.f; lc[tid] = 0.f; }
  __syncthreads();
  int i = blockIdx.x * blockDim.x + tid;
  if (i < N) {
    float a = agg[i], f = 0.f;
    for (int k = 0; k < H; ++k) {
      float hh = fmaf(a, sWl[k], sbl[k]);
      f = fmaf(fmaxf(hh, 0.f), sWo[k], f);
    }
    int g = batch[i];
    atomicAdd(&ls[g], f);
    atomicAdd(&lc[g], 1.f);
  }
  __syncthreads();
  if (tid < GMAX && lc[tid] != 0.f) {
    atomicAdd(&gsum[tid], ls[tid]);
    atomicAdd(&gcnt[tid], lc[tid]);
  }
}

__global__ void fb_final(const float* __restrict__ gsum,
                         const float* __restrict__ gcnt,
                         const float* __restrict__ b_out,
                         float* __restrict__ out, int G) {
  int g = blockIdx.x * blockDim.x + threadIdx.x;
  if (g < G) out[g] = fmaxf(gsum[g] / fmaxf(gcnt[g], 1.f) + b_out[0], 0.f);
}

// ---------------- launch ----------------

extern "C" void kernel_launch(void* const* d_in, const int* in_sizes, int n_in,
                              void* d_out, int out_size, void* d_ws, size_t ws_size,
                              hipStream_t stream) {
  const float* x     = (const float*)d_in[0];
  const int*   ei    = (const int*)d_in[1];
  const int*   batch = (const int*)d_in[2];
  const float* Wl    = (const float*)d_in[3];
  const float* bl    = (const float*)d_in[4];
  const float* Wo    = (const float*)d_in[5];
  const float* bo    = (const float*)d_in[6];
  float* out = (float*)d_out;

  int N = in_sizes[0];        // 100000
  int E = in_sizes[1] / 2;    // 3200000
  int H = in_sizes[3];        // 256
  int G = out_size;           // 128

  int RANGE = (N + RNG - 1) / RNG;           // 12500
  int Q     = E >> 2;
  int QpC   = (Q + CHK - 1) / CHK;           // 8334 quads/chunk

  // ws layout (words): gsum[GMAX] | gcnt[GMAX] | done[..] | pad -> HDRW |
  //                    partial[RNG*CHK][RLDS]
  size_t need = ((size_t)HDRW + (size_t)RNG * CHK * RLDS) * 4u;

  if (RANGE <= RLDS && H <= HMAX && G <= GMAX && ws_size >= need && N > 0) {
    float*    w     = (float*)d_ws;
    float*    gsum  = w;
    float*    gcnt  = w + GMAX;
    unsigned* done  = (unsigned*)(w + 2 * GMAX);
    float*    partial = w + HDRW;

    p1_scatter<<<RNG * CHK, 512, 0, stream>>>(ei, x, partial, gsum, gcnt,
                                              done, E, N, RANGE, QpC);
    int BPR = (RANGE + 255) / 256;           // blocks per range (49)
    p2_node<<<RNG * BPR, 256, 0, stream>>>(partial, batch, Wl, bl, Wo, bo,
                                           gsum, gcnt, done, out,
                                           N, H, G, RANGE, BPR);
  } else {
    float* agg  = (float*)d_ws;
    float* gsum = agg + N;
    float* gcnt = gsum + GMAX;
    hipMemsetAsync(d_ws, 0, ((size_t)N + 2 * GMAX) * 4u, stream);
    fb_scatter<<<(E + 255) / 256, 256, 0, stream>>>(ei, x, agg, E);
    fb_node<<<(N + 255) / 256, 256, 0, stream>>>(agg, batch, Wl, bl, Wo,
                                                 gsum, gcnt, N, H);
    fb_final<<<1, 256, 0, stream>>>(gsum, gcnt, bo, out, G);
  }
}

// Round 8
// 121.007 us; speedup vs baseline: 2.7074x; 1.0350x over previous
//
#include <hip/hip_runtime.h>

// N=100000, E=3200000, H=256, G=128.
// R14: p1 at 100% occupancy + smaller partial buffer. Evidence chain:
//  - R9/R10: global f32 atomics are memory-side at ANY scope (~20G/s) -> LDS agg.
//  - R11: grid.sync ~50us each -> no cooperative fusion; ~88us of harness
//    256MiB poison fills (2x44us) sit INSIDE the timed window (cross-round
//    arithmetic R9/R11); MLP-kernel cost is ~2us (R9: n_node ~2us).
//  - R12->R13: occupancy 2->3 blk/CU moved p1 below top-5 (<43us) but CHK 96
//    grew partial traffic 27->40MB each way; total flat.
// This round: p1 BLK 1024, CHK 64 -> grid 512 = 2 blocks/CU x 16 waves =
// 32 waves/CU (100% occ; LDS 52KBx2=104KB); partial back to 26.7MB each way;
// p2 sums 64 slabs. Same-chunk blocks {r*64+j} are = j (mod 8) -> one XCD,
// chunk re-reads L2-hot (8 x 400KB = 3.2MB < 4MB L2/XCD).
//  P1: block (r,j) streams edge chunk j (int4, coalesced), filters dst in
//      range r (1-compare unsigned test), acc[dst-lo] += x[src] (LDS f32
//      atomics), slab -> partial[r*CHK+j] coalesced. Block 0 zeroes header.
//  P2: a = sum_j partial[r][j][li] (64 coalesced strided reads, unroll 8),
//      collapsed MLP f(a)=sum_k relu(a*Wl[k]+bl[k])*Wo[k], per-graph LDS
//      pooling, sparse device atomics, ticket epilogue -> relu(mean + b_out).

#define GMAX 128       // max graphs
#define HMAX 256       // max hidden dim
#define RNG  8         // node ranges (LDS-sized)
#define CHK  64        // edge chunks (%8==0 for XCD affinity; grid=512)
#define BLK1 1024      // p1 threads (16 waves; 2 blocks/CU = 32 waves = 100%)
#define RLDS 13056     // LDS accumulator words per range (>= ceil(N/RNG))
#define HDRW 272       // header words (gsum,gcnt,done + pad to 16B)

// ---------------- main path ----------------

__global__ __launch_bounds__(BLK1, 8) void p1_scatter(
    const int* __restrict__ ei, const float* __restrict__ x,
    float* __restrict__ partial, float* __restrict__ gsum,
    float* __restrict__ gcnt, unsigned* __restrict__ done,
    int E, int N, int RANGE, int QpC) {
  __shared__ __align__(16) float acc[RLDS];
  int tid = threadIdx.x, blk = blockIdx.x;
  int r = blk / CHK;         // node range id   [0,RNG)
  int j = blk % CHK;         // edge chunk id   [0,CHK) -> XCD = j%8
  for (int i = tid; i < RLDS; i += BLK1) acc[i] = 0.f;
  if (blk == 0) {            // zero epilogue state for P2 (ws is poisoned)
    if (tid < GMAX) { gsum[tid] = 0.f; gcnt[tid] = 0.f; }
    if (tid == 0) done[0] = 0u;
  }
  __syncthreads();

  int lo = r * RANGE;
  unsigned span = (unsigned)(min(lo + RANGE, N) - lo);
  int Q = E >> 2;
  int q0 = j * QpC, q1 = min(q0 + QpC, Q);
  const int4* s4 = (const int4*)ei;
  const int4* d4 = (const int4*)(ei + E);
#pragma unroll 2
  for (int q = q0 + tid; q < q1; q += BLK1) {
    int4 s = s4[q];
    int4 d = d4[q];
    unsigned ux = (unsigned)(d.x - lo), uy = (unsigned)(d.y - lo);
    unsigned uz = (unsigned)(d.z - lo), uw = (unsigned)(d.w - lo);
    if (ux < span) atomicAdd(&acc[ux], x[s.x]);
    if (uy < span) atomicAdd(&acc[uy], x[s.y]);
    if (uz < span) atomicAdd(&acc[uz], x[s.z]);
    if (uw < span) atomicAdd(&acc[uw], x[s.w]);
  }
  if (j == 0) {              // tail edges (E % 4): the RNG j==0 blocks filter
    for (int e = (Q << 2) + tid; e < E; e += BLK1) {
      unsigned u = (unsigned)(ei[E + e] - lo);
      if (u < span) atomicAdd(&acc[u], x[ei[e]]);
    }
  }
  __syncthreads();

  // coalesced slab dump (full RLDS incl zero pad; P2 reads only li < RANGE)
  float4* dst = (float4*)(partial + (size_t)blk * RLDS);
  const float4* a4 = (const float4*)acc;
  for (int i = tid; i < RLDS / 4; i += BLK1) dst[i] = a4[i];
}

__global__ __launch_bounds__(256, 4) void p2_node(
    const float* __restrict__ partial, const int* __restrict__ batch,
    const float* __restrict__ Wl, const float* __restrict__ bl,
    const float* __restrict__ Wo, const float* __restrict__ bo,
    float* __restrict__ gsum, float* __restrict__ gcnt,
    unsigned* __restrict__ done, float* __restrict__ out,
    int N, int H, int G, int RANGE, int BPR) {
  __shared__ float sWl[HMAX], sbl[HMAX], sWo[HMAX];
  __shared__ float ls[GMAX], lc[GMAX];
  __shared__ unsigned ticket;
  int tid = threadIdx.x, blk = blockIdx.x;
  if (tid < H) { sWl[tid] = Wl[tid]; sbl[tid] = bl[tid]; sWo[tid] = Wo[tid]; }
  if (tid < GMAX) { ls[tid] = 0.f; lc[tid] = 0.f; }
  __syncthreads();

  int r = blk / BPR;
  int li = (blk % BPR) * 256 + tid;
  int node = r * RANGE + li;
  if (li < RANGE && node < N) {
    // CHK-way partial sum: coalesced across lanes, 8-deep ILP across slabs
    const float* p = partial + (size_t)(r * CHK) * RLDS + li;
    float a = 0.f;
#pragma unroll 8
    for (int c = 0; c < CHK; ++c) a += p[(size_t)c * RLDS];
    float f = 0.f;
#pragma unroll 8
    for (int k = 0; k < H; ++k) {
      float hh = fmaf(a, sWl[k], sbl[k]);
      f = fmaf(fmaxf(hh, 0.f), sWo[k], f);
    }
    int g = batch[node];
    atomicAdd(&ls[g], f);
    atomicAdd(&lc[g], 1.f);
  }
  __syncthreads();
  if (tid < GMAX && lc[tid] != 0.f) {
    atomicAdd(&gsum[tid], ls[tid]);   // sparse: batch sorted -> ~1-2 graphs/blk
    atomicAdd(&gcnt[tid], lc[tid]);
  }
  __syncthreads();
  if (tid == 0)
    ticket = __hip_atomic_fetch_add(done, 1u, __ATOMIC_ACQ_REL,
                                    __HIP_MEMORY_SCOPE_AGENT);
  __syncthreads();
  if (ticket == gridDim.x - 1 && tid < G) {
    float s = __hip_atomic_load(&gsum[tid], __ATOMIC_RELAXED, __HIP_MEMORY_SCOPE_AGENT);
    float c = __hip_atomic_load(&gcnt[tid], __ATOMIC_RELAXED, __HIP_MEMORY_SCOPE_AGENT);
    out[tid] = fmaxf(s / fmaxf(c, 1.f) + bo[0], 0.f);
  }
}

// ---------------- fallback path (guards fail) ----------------

__global__ __launch_bounds__(256) void fb_scatter(const int* __restrict__ ei,
                                                  const float* __restrict__ x,
                                                  float* __restrict__ agg, int E) {
  int t = blockIdx.x * blockDim.x + threadIdx.x;
  if (t < E) atomicAdd(&agg[ei[E + t]], x[ei[t]]);
}

__global__ __launch_bounds__(256) void fb_node(const float* __restrict__ agg,
                                               const int* __restrict__ batch,
                                               const float* __restrict__ Wl,
                                               const float* __restrict__ bl,
                                               const float* __restrict__ Wo,
                                               float* __restrict__ gsum,
                                               float* __restrict__ gcnt, int N, int H) {
  __shared__ float sWl[HMAX], sbl[HMAX], sWo[HMAX];
  __shared__ float ls[GMAX], lc[GMAX];
  int tid = threadIdx.x;
  if (tid < H) { sWl[tid] = Wl[tid]; sbl[tid] = bl[tid]; sWo[tid] = Wo[tid]; }
  if (tid < GMAX) { ls[tid] = 0.f; lc[tid] = 0.f; }
  __syncthreads();
  int i = blockIdx.x * blockDim.x + tid;
  if (i < N) {
    float a = agg[i], f = 0.f;
    for (int k = 0; k < H; ++k) {
      float hh = fmaf(a, sWl[k], sbl[k]);
      f = fmaf(fmaxf(hh, 0.f), sWo[k], f);
    }
    int g = batch[i];
    atomicAdd(&ls[g], f);
    atomicAdd(&lc[g], 1.f);
  }
  __syncthreads();
  if (tid < GMAX && lc[tid] != 0.f) {
    atomicAdd(&gsum[tid], ls[tid]);
    atomicAdd(&gcnt[tid], lc[tid]);
  }
}

__global__ void fb_final(const float* __restrict__ gsum,
                         const float* __restrict__ gcnt,
                         const float* __restrict__ b_out,
                         float* __restrict__ out, int G) {
  int g = blockIdx.x * blockDim.x + threadIdx.x;
  if (g < G) out[g] = fmaxf(gsum[g] / fmaxf(gcnt[g], 1.f) + b_out[0], 0.f);
}

// ---------------- launch ----------------

extern "C" void kernel_launch(void* const* d_in, const int* in_sizes, int n_in,
                              void* d_out, int out_size, void* d_ws, size_t ws_size,
                              hipStream_t stream) {
  const float* x     = (const float*)d_in[0];
  const int*   ei    = (const int*)d_in[1];
  const int*   batch = (const int*)d_in[2];
  const float* Wl    = (const float*)d_in[3];
  const float* bl    = (const float*)d_in[4];
  const float* Wo    = (const float*)d_in[5];
  const float* bo    = (const float*)d_in[6];
  float* out = (float*)d_out;

  int N = in_sizes[0];        // 100000
  int E = in_sizes[1] / 2;    // 3200000
  int H = in_sizes[3];        // 256
  int G = out_size;           // 128

  int RANGE = (N + RNG - 1) / RNG;           // 12500
  int Q     = E >> 2;
  int QpC   = (Q + CHK - 1) / CHK;           // 12500 quads/chunk

  // ws layout (words): gsum[GMAX] | gcnt[GMAX] | done[..] | pad -> HDRW |
  //                    partial[RNG*CHK][RLDS]
  size_t need = ((size_t)HDRW + (size_t)RNG * CHK * RLDS) * 4u;

  if (RANGE <= RLDS && H <= HMAX && G <= GMAX && ws_size >= need && N > 0) {
    float*    w     = (float*)d_ws;
    float*    gsum  = w;
    float*    gcnt  = w + GMAX;
    unsigned* done  = (unsigned*)(w + 2 * GMAX);
    float*    partial = w + HDRW;

    p1_scatter<<<RNG * CHK, BLK1, 0, stream>>>(ei, x, partial, gsum, gcnt,
                                               done, E, N, RANGE, QpC);
    int BPR = (RANGE + 255) / 256;           // blocks per range (49)
    p2_node<<<RNG * BPR, 256, 0, stream>>>(partial, batch, Wl, bl, Wo, bo,
                                           gsum, gcnt, done, out,
                                           N, H, G, RANGE, BPR);
  } else {
    float* agg  = (float*)d_ws;
    float* gsum = agg + N;
    float* gcnt = gsum + GMAX;
    hipMemsetAsync(d_ws, 0, ((size_t)N + 2 * GMAX) * 4u, stream);
    fb_scatter<<<(E + 255) / 256, 256, 0, stream>>>(ei, x, agg, E);
    fb_node<<<(N + 255) / 256, 256, 0, stream>>>(agg, batch, Wl, bl, Wo,
                                                 gsum, gcnt, N, H);
    fb_final<<<1, 256, 0, stream>>>(gsum, gcnt, bo, out, G);
  }
}

// Round 9
// 119.793 us; speedup vs baseline: 2.7349x; 1.0101x over previous
//
#include <hip/hip_runtime.h>

// N=100000, E=3200000, H=256, G=128.
// R15: p1 latency micro-opts. Evidence chain:
//  - R9/R10: global f32 atomics memory-side at ANY scope (~20G/s) -> LDS agg.
//  - R11: grid.sync ~50us -> no cooperative fusion; harness 256MiB poison
//    fills (~80-90us) sit INSIDE the timed window (R9/R11 arithmetic).
//  - R12->R14: occupancy 34%->100% took p1 44.2 -> ~24us est; total 121.0.
//    Occupancy lever exhausted; p1 still ~4x its traffic floor -> gather
//    latency + L2 request pressure.
// This round (structure unchanged: RNG=8 x CHK=64, BLK1=1024, 2 blk/CU):
//  (a) dst-first predicated src load: P(all 4 dst miss range) = (7/8)^4 =
//      0.586 -> skip 59% of src int4 loads (less L2 issue pressure).
//  (b) unroll 4 (was 2): 16 outstanding gather chains/wave to hide ~200cy
//      L2 latency at fixed wave count.
//  (c) RLDS 13056->12544 (>=12500, %64==0): slab round-trip -4%; p2 unroll 16.
//  P1: block (r,j) streams edge chunk j, filters dst in range r (1-compare
//      unsigned test), acc[dst-lo] += x[src] (LDS f32 atomics, fire-and-
//      forget), slab -> partial[r*CHK+j] coalesced. Block 0 zeroes header.
//      Same-chunk blocks {r*64+j} = j (mod 8) -> one XCD, chunk re-reads
//      L2-hot (8 x 400KB = 3.2MB < 4MB L2/XCD).
//  P2: a = sum_j partial[r][j][li] (64 coalesced strided reads), collapsed
//      MLP f(a)=sum_k relu(a*Wl[k]+bl[k])*Wo[k], per-graph LDS pooling,
//      sparse device atomics, ticket epilogue -> relu(mean + b_out).

#define GMAX 128       // max graphs
#define HMAX 256       // max hidden dim
#define RNG  8         // node ranges (LDS-sized)
#define CHK  64        // edge chunks (%8==0 for XCD affinity; grid=512)
#define BLK1 1024      // p1 threads (16 waves; 2 blocks/CU = 32 waves = 100%)
#define RLDS 12544     // LDS accumulator words per range (>= ceil(N/RNG), %64==0)
#define HDRW 272       // header words (gsum,gcnt,done + pad to 16B)

// ---------------- main path ----------------

__global__ __launch_bounds__(BLK1, 8) void p1_scatter(
    const int* __restrict__ ei, const float* __restrict__ x,
    float* __restrict__ partial, float* __restrict__ gsum,
    float* __restrict__ gcnt, unsigned* __restrict__ done,
    int E, int N, int RANGE, int QpC) {
  __shared__ __align__(16) float acc[RLDS];
  int tid = threadIdx.x, blk = blockIdx.x;
  int r = blk / CHK;         // node range id   [0,RNG)
  int j = blk % CHK;         // edge chunk id   [0,CHK) -> XCD = j%8
  for (int i = tid; i < RLDS; i += BLK1) acc[i] = 0.f;
  if (blk == 0) {            // zero epilogue state for P2 (ws is poisoned)
    if (tid < GMAX) { gsum[tid] = 0.f; gcnt[tid] = 0.f; }
    if (tid == 0) done[0] = 0u;
  }
  __syncthreads();

  int lo = r * RANGE;
  unsigned span = (unsigned)(min(lo + RANGE, N) - lo);
  int Q = E >> 2;
  int q0 = j * QpC, q1 = min(q0 + QpC, Q);
  const int4* s4 = (const int4*)ei;
  const int4* d4 = (const int4*)(ei + E);
#pragma unroll 4
  for (int q = q0 + tid; q < q1; q += BLK1) {
    int4 d = d4[q];
    unsigned ux = (unsigned)(d.x - lo), uy = (unsigned)(d.y - lo);
    unsigned uz = (unsigned)(d.z - lo), uw = (unsigned)(d.w - lo);
    if ((ux < span) | (uy < span) | (uz < span) | (uw < span)) {
      int4 s = s4[q];        // src quad only when some lane-edge passes (41%)
      if (ux < span) atomicAdd(&acc[ux], x[s.x]);
      if (uy < span) atomicAdd(&acc[uy], x[s.y]);
      if (uz < span) atomicAdd(&acc[uz], x[s.z]);
      if (uw < span) atomicAdd(&acc[uw], x[s.w]);
    }
  }
  if (j == 0) {              // tail edges (E % 4): the RNG j==0 blocks filter
    for (int e = (Q << 2) + tid; e < E; e += BLK1) {
      unsigned u = (unsigned)(ei[E + e] - lo);
      if (u < span) atomicAdd(&acc[u], x[ei[e]]);
    }
  }
  __syncthreads();

  // coalesced slab dump (full RLDS incl zero pad; P2 reads only li < RANGE)
  float4* dst = (float4*)(partial + (size_t)blk * RLDS);
  const float4* a4 = (const float4*)acc;
  for (int i = tid; i < RLDS / 4; i += BLK1) dst[i] = a4[i];
}

__global__ __launch_bounds__(256, 4) void p2_node(
    const float* __restrict__ partial, const int* __restrict__ batch,
    const float* __restrict__ Wl, const float* __restrict__ bl,
    const float* __restrict__ Wo, const float* __restrict__ bo,
    float* __restrict__ gsum, float* __restrict__ gcnt,
    unsigned* __restrict__ done, float* __restrict__ out,
    int N, int H, int G, int RANGE, int BPR) {
  __shared__ float sWl[HMAX], sbl[HMAX], sWo[HMAX];
  __shared__ float ls[GMAX], lc[GMAX];
  __shared__ unsigned ticket;
  int tid = threadIdx.x, blk = blockIdx.x;
  if (tid < H) { sWl[tid] = Wl[tid]; sbl[tid] = bl[tid]; sWo[tid] = Wo[tid]; }
  if (tid < GMAX) { ls[tid] = 0.f; lc[tid] = 0.f; }
  __syncthreads();

  int r = blk / BPR;
  int li = (blk % BPR) * 256 + tid;
  int node = r * RANGE + li;
  if (li < RANGE && node < N) {
    // CHK-way partial sum: coalesced across lanes, 16-deep ILP across slabs
    const float* p = partial + (size_t)(r * CHK) * RLDS + li;
    float a = 0.f;
#pragma unroll 16
    for (int c = 0; c < CHK; ++c) a += p[(size_t)c * RLDS];
    float f = 0.f;
#pragma unroll 8
    for (int k = 0; k < H; ++k) {
      float hh = fmaf(a, sWl[k], sbl[k]);
      f = fmaf(fmaxf(hh, 0.f), sWo[k], f);
    }
    int g = batch[node];
    atomicAdd(&ls[g], f);
    atomicAdd(&lc[g], 1.f);
  }
  __syncthreads();
  if (tid < GMAX && lc[tid] != 0.f) {
    atomicAdd(&gsum[tid], ls[tid]);   // sparse: batch sorted -> ~1-2 graphs/blk
    atomicAdd(&gcnt[tid], lc[tid]);
  }
  __syncthreads();
  if (tid == 0)
    ticket = __hip_atomic_fetch_add(done, 1u, __ATOMIC_ACQ_REL,
                                    __HIP_MEMORY_SCOPE_AGENT);
  __syncthreads();
  if (ticket == gridDim.x - 1 && tid < G) {
    float s = __hip_atomic_load(&gsum[tid], __ATOMIC_RELAXED, __HIP_MEMORY_SCOPE_AGENT);
    float c = __hip_atomic_load(&gcnt[tid], __ATOMIC_RELAXED, __HIP_MEMORY_SCOPE_AGENT);
    out[tid] = fmaxf(s / fmaxf(c, 1.f) + bo[0], 0.f);
  }
}

// ---------------- fallback path (guards fail) ----------------

__global__ __launch_bounds__(256) void fb_scatter(const int* __restrict__ ei,
                                                  const float* __restrict__ x,
                                                  float* __restrict__ agg, int E) {
  int t = blockIdx.x * blockDim.x + threadIdx.x;
  if (t < E) atomicAdd(&agg[ei[E + t]], x[ei[t]]);
}

__global__ __launch_bounds__(256) void fb_node(const float* __restrict__ agg,
                                               const int* __restrict__ batch,
                                               const float* __restrict__ Wl,
                                               const float* __restrict__ bl,
                                               const float* __restrict__ Wo,
                                               float* __restrict__ gsum,
                                               float* __restrict__ gcnt, int N, int H) {
  __shared__ float sWl[HMAX], sbl[HMAX], sWo[HMAX];
  __shared__ float ls[GMAX], lc[GMAX];
  int tid = threadIdx.x;
  if (tid < H) { sWl[tid] = Wl[tid]; sbl[tid] = bl[tid]; sWo[tid] = Wo[tid]; }
  if (tid < GMAX) { ls[tid] = 0.f; lc[tid] = 0.f; }
  __syncthreads();
  int i = blockIdx.x * blockDim.x + tid;
  if (i < N) {
    float a = agg[i], f = 0.f;
    for (int k = 0; k < H; ++k) {
      float hh = fmaf(a, sWl[k], sbl[k]);
      f = fmaf(fmaxf(hh, 0.f), sWo[k], f);
    }
    int g = batch[i];
    atomicAdd(&ls[g], f);
    atomicAdd(&lc[g], 1.f);
  }
  __syncthreads();
  if (tid < GMAX && lc[tid] != 0.f) {
    atomicAdd(&gsum[tid], ls[tid]);
    atomicAdd(&gcnt[tid], lc[tid]);
  }
}

__global__ void fb_final(const float* __restrict__ gsum,
                         const float* __restrict__ gcnt,
                         const float* __restrict__ b_out,
                         float* __restrict__ out, int G) {
  int g = blockIdx.x * blockDim.x + threadIdx.x;
  if (g < G) out[g] = fmaxf(gsum[g] / fmaxf(gcnt[g], 1.f) + b_out[0], 0.f);
}

// ---------------- launch ----------------

extern "C" void kernel_launch(void* const* d_in, const int* in_sizes, int n_in,
                              void* d_out, int out_size, void* d_ws, size_t ws_size,
                              hipStream_t stream) {
  const float* x     = (const float*)d_in[0];
  const int*   ei    = (const int*)d_in[1];
  const int*   batch = (const int*)d_in[2];
  const float* Wl    = (const float*)d_in[3];
  const float* bl    = (const float*)d_in[4];
  const float* Wo    = (const float*)d_in[5];
  const float* bo    = (const float*)d_in[6];
  float* out = (float*)d_out;

  int N = in_sizes[0];        // 100000
  int E = in_sizes[1] / 2;    // 3200000
  int H = in_sizes[3];        // 256
  int G = out_size;           // 128

  int RANGE = (N + RNG - 1) / RNG;           // 12500
  int Q     = E >> 2;
  int QpC   = (Q + CHK - 1) / CHK;           // 12500 quads/chunk

  // ws layout (words): gsum[GMAX] | gcnt[GMAX] | done[..] | pad -> HDRW |
  //                    partial[RNG*CHK][RLDS]
  size_t need = ((size_t)HDRW + (size_t)RNG * CHK * RLDS) * 4u;

  if (RANGE <= RLDS && H <= HMAX && G <= GMAX && ws_size >= need && N > 0) {
    float*    w     = (float*)d_ws;
    float*    gsum  = w;
    float*    gcnt  = w + GMAX;
    unsigned* done  = (unsigned*)(w + 2 * GMAX);
    float*    partial = w + HDRW;

    p1_scatter<<<RNG * CHK, BLK1, 0, stream>>>(ei, x, partial, gsum, gcnt,
                                               done, E, N, RANGE, QpC);
    int BPR = (RANGE + 255) / 256;           // blocks per range (49)
    p2_node<<<RNG * BPR, 256, 0, stream>>>(partial, batch, Wl, bl, Wo, bo,
                                           gsum, gcnt, done, out,
                                           N, H, G, RANGE, BPR);
  } else {
    float* agg  = (float*)d_ws;
    float* gsum = agg + N;
    float* gcnt = gsum + GMAX;
    hipMemsetAsync(d_ws, 0, ((size_t)N + 2 * GMAX) * 4u, stream);
    fb_scatter<<<(E + 255) / 256, 256, 0, stream>>>(ei, x, agg, E);
    fb_node<<<(N + 255) / 256, 256, 0, stream>>>(agg, batch, Wl, bl, Wo,
                                                 gsum, gcnt, N, H);
    fb_final<<<1, 256, 0, stream>>>(gsum, gcnt, bo, out, G);
  }
}